// Round 12
// baseline (631.663 us; speedup 1.0000x reference)
//
#include <hip/hip_runtime.h>
#include <cstdint>
#include <cstddef>

#define NEXPERT 32
#define KIN 256
#define NOUT 256
#define NTOK 524288
#define TPB 8                 // tiles per block; grid = NTOK/(64*TPB) = 1024
#define GSTEPS (TPB * 4)      // global K-steps per block

typedef float f32x4 __attribute__((ext_vector_type(4)));
typedef __bf16 bf16x8 __attribute__((ext_vector_type(8)));
typedef unsigned short u16;
typedef u16 u16x8 __attribute__((ext_vector_type(8)));
typedef unsigned int u32;

union BF8 { u16x8 u; bf16x8 b; };

__device__ __forceinline__ u16 f2bf(float f) {
  unsigned u = __float_as_uint(f);
  return (u16)((u + 0x7FFFu + ((u >> 16) & 1u)) >> 16);  // RNE
}

__device__ __forceinline__ void cvt8(const float4& x, const float4& y, BF8& o) {
  o.u[0]=f2bf(x.x); o.u[1]=f2bf(x.y); o.u[2]=f2bf(x.z); o.u[3]=f2bf(x.w);
  o.u[4]=f2bf(y.x); o.u[5]=f2bf(y.y); o.u[6]=f2bf(y.z); o.u[7]=f2bf(y.w);
}

#define GLDS(gp, lp) __builtin_amdgcn_global_load_lds(                      \
    (const __attribute__((address_space(1))) u32*)(gp),                      \
    (__attribute__((address_space(3))) u32*)(u32)(uintptr_t)(lp), 16, 0, 0)

#define VMW(n) asm volatile("s_waitcnt vmcnt(" n ")" ::: "memory")

// ---- prologue: pack W fp32 -> bf16 in MFMA-fragment order ----
__global__ void pack_w_kernel(const float* __restrict__ w, u16* __restrict__ wb) {
  const int t    = blockIdx.x * 256 + threadIdx.x;   // 0..262143
  const int lane = t & 63;
  const int n16  = (t >> 6) & 15;
  const int kc   = (t >> 10) & 7;
  const int e    = t >> 13;
  const float* src = w + (size_t)e * 65536 + (size_t)(n16 * 16 + (lane & 15)) * 256
                       + kc * 32 + (lane >> 4) * 8;
  const float4 a = *reinterpret_cast<const float4*>(src);
  const float4 b = *reinterpret_cast<const float4*>(src + 4);
  u16x8 h;
  h[0]=f2bf(a.x); h[1]=f2bf(a.y); h[2]=f2bf(a.z); h[3]=f2bf(a.w);
  h[4]=f2bf(b.x); h[5]=f2bf(b.y); h[6]=f2bf(b.z); h[7]=f2bf(b.w);
  *reinterpret_cast<u16x8*>(wb + (size_t)t * 8) = h;
}

// ---- B fragments for one K-step (2 chunks x 4 n), coalesced 1KB loads ----
template<bool WSBF>
__device__ __forceinline__ void loadBstep(const u16* wEL, const float* wF,
                                          int wv, int l15, int lg, int s,
                                          BF8 (&d)[2][4]) {
  if (WSBF) {
#pragma unroll
    for (int c = 0; c < 2; ++c)
#pragma unroll
      for (int n = 0; n < 4; ++n)
        d[c][n].u = *reinterpret_cast<const u16x8*>(
            wEL + (size_t)((2 * s + c) * 16 + (wv << 2) + n) * 512);
  } else {
#pragma unroll
    for (int c = 0; c < 2; ++c)
#pragma unroll
      for (int n = 0; n < 4; ++n) {
        const float4* p = reinterpret_cast<const float4*>(
            wF + (size_t)((wv << 6) + (n << 4) + l15) * KIN + (2 * s + c) * 32 + lg * 8);
        cvt8(p[0], p[1], d[c][n]);
      }
  }
}

// ---- one K-step of MFMA from staged fp32 LDS buffer (swizzled read) ----
__device__ __forceinline__ void computeStep(const char* sAc, int buf, int l15, int lg,
                                            const BF8 (&bfr)[2][4], f32x4 (&acc)[4][4]) {
  const char* abase = sAc + buf * 16384 + l15 * 256;
#pragma unroll
  for (int c = 0; c < 2; ++c) {
    BF8 af[4];
#pragma unroll
    for (int m = 0; m < 4; ++m) {
      const int g0 = (c << 3) + (lg << 1);
      const f32x4 fa = *reinterpret_cast<const f32x4*>(abase + m * 4096 + (((g0    ) ^ l15) << 4));
      const f32x4 fb = *reinterpret_cast<const f32x4*>(abase + m * 4096 + (((g0 + 1) ^ l15) << 4));
      af[m].b[0]=(__bf16)fa[0]; af[m].b[1]=(__bf16)fa[1];
      af[m].b[2]=(__bf16)fa[2]; af[m].b[3]=(__bf16)fa[3];
      af[m].b[4]=(__bf16)fb[0]; af[m].b[5]=(__bf16)fb[1];
      af[m].b[6]=(__bf16)fb[2]; af[m].b[7]=(__bf16)fb[3];
    }
#pragma unroll
    for (int m = 0; m < 4; ++m)
#pragma unroll
      for (int n = 0; n < 4; ++n)
        acc[m][n] = __builtin_amdgcn_mfma_f32_16x16x32_bf16(
            af[m].b, bfr[c][n].b, acc[m][n], 0, 0, 0);
  }
}

// ---- boundary-tile slow path: per-lane global A gather, B inline ----
template<bool WSBF>
__device__ void redoRun2(const float* __restrict__ inp, const u16* __restrict__ wpk,
                         const float* w32, int t0, int rb, int re, int e,
                         float* __restrict__ out, int wv, int l15, int lg, int lane) {
  const u16*   wEL = wpk + ((size_t)e << 16) + (lane << 3);
  const float* wF  = w32 + ((size_t)e << 16);
  f32x4 acc[4][4];
  const f32x4 zero = {0.f, 0.f, 0.f, 0.f};
#pragma unroll
  for (int m = 0; m < 4; ++m)
#pragma unroll
    for (int n = 0; n < 4; ++n) acc[m][n] = zero;
#pragma unroll
  for (int q = 0; q < 8; ++q) {      // k-chunks of 32
    BF8 bq[4];
    if (WSBF) {
#pragma unroll
      for (int n = 0; n < 4; ++n)
        bq[n].u = *reinterpret_cast<const u16x8*>(
            wEL + (size_t)(q * 16 + (wv << 2) + n) * 512);
    } else {
#pragma unroll
      for (int n = 0; n < 4; ++n) {
        const float4* p = reinterpret_cast<const float4*>(
            wF + (size_t)((wv << 6) + (n << 4) + l15) * KIN + q * 32 + lg * 8);
        cvt8(p[0], p[1], bq[n]);
      }
    }
    BF8 af[4];
#pragma unroll
    for (int m = 0; m < 4; ++m) {
      const float* p = inp + (size_t)(t0 + m * 16 + l15) * KIN + q * 32 + lg * 8;
      cvt8(*reinterpret_cast<const float4*>(p), *reinterpret_cast<const float4*>(p + 4), af[m]);
    }
#pragma unroll
    for (int m = 0; m < 4; ++m)
#pragma unroll
      for (int n = 0; n < 4; ++n)
        acc[m][n] = __builtin_amdgcn_mfma_f32_16x16x32_bf16(
            af[m].b, bq[n].b, acc[m][n], 0, 0, 0);
  }
#pragma unroll
  for (int m = 0; m < 4; ++m) {
    const int rbase = t0 + (m << 4) + (lg << 2);
#pragma unroll
    for (int n = 0; n < 4; ++n) {
      float* op = out + (size_t)rbase * NOUT + (wv << 6) + (n << 4) + l15;
#pragma unroll
      for (int j = 0; j < 4; ++j) {
        const int rg = rbase + j;
        if (rg >= rb && rg < re) op[(size_t)j * NOUT] = acc[m][n][j];
      }
    }
  }
}

// ---- producer-consumer grouped GEMM ----
// block = 320 threads: waves 0..3 compute (64-col slices), wave 4 stages A.
// A: 4 x 16KB LDS bufs; producer GLDS 2 bufs ahead, flags via LDS seq after
// counted vmcnt. Consumers: poll flag + counted vmcnt(8) on own B loads only.
// No s_barrier in steady state.
template<bool WSBF>
__global__ __launch_bounds__(320, 3)
void moe_gemm_kernel(const float* __restrict__ inp,
                     const float* w32,
                     const u16* __restrict__ wpk,
                     const int* __restrict__ counts,
                     float* __restrict__ out)
{
  __shared__ float sA[4 * 64 * 64];   // 64 KB
  __shared__ int sSync[8];            // [0..3] flag = last staged g+1; [4..7] done count

  const int tid  = threadIdx.x;
  const int lane = tid & 63;
  const int wv   = tid >> 6;          // 0..3 consumers, 4 producer
  const int l15  = lane & 15;
  const int lg   = lane >> 4;

  if (tid < 8) sSync[tid] = 0;
  __syncthreads();                    // the only barrier

  const int blk0 = blockIdx.x * (64 * TPB);
  char* const sAc = reinterpret_cast<char*>(sA);
  volatile int* vf = sSync;           // flags
  volatile int* vd = sSync + 4;       // done counters

  if (wv == 4) {
    // ================= PRODUCER =================
    const char* inp8 = reinterpret_cast<const char*>(inp);
    const int rowoff = lane >> 4, swz = lane & 15;
    int P[4];
#pragma unroll
    for (int j = 0; j < 4; ++j) {
      const int rr = j * 4 + rowoff;
      P[j] = rr * 1024 + ((swz ^ rr) << 4);   // per-lane row+swizzle byte offset
    }
    auto STAGE = [&](int g) {
      const char* src = inp8 + ((size_t)(blk0 + (g >> 2) * 64) << 10) + ((g & 3) << 8);
      char* dst = sAc + ((g & 3) << 14);
#pragma unroll
      for (int i = 0; i < 16; ++i)
        GLDS((const float*)(src + ((size_t)(i >> 2) << 14) + P[i & 3]), dst + i * 1024);
    };

    STAGE(0); STAGE(1);
    VMW("16"); asm volatile("" ::: "memory");
    if (lane == 0) vf[0] = 1;
    for (int g = 2; g < GSTEPS; ++g) {
      const int b = g & 3, need = (g >> 2) * 4;
      while (vd[b] < need) __builtin_amdgcn_s_sleep(2);
      asm volatile("" ::: "memory");
      STAGE(g);
      VMW("32"); asm volatile("" ::: "memory");
      if (lane == 0) vf[(g - 2) & 3] = g - 1;
    }
    VMW("16"); asm volatile("" ::: "memory");
    if (lane == 0) vf[(GSTEPS - 2) & 3] = GSTEPS - 1;
    VMW("0");  asm volatile("" ::: "memory");
    if (lane == 0) vf[(GSTEPS - 1) & 3] = GSTEPS;
    return;
  }

  // ================= CONSUMERS =================
  // per-wave INCLUSIVE cumsum of counts via shuffle scan (int32/int64 probe)
  const long long* c64 = reinterpret_cast<const long long*>(counts);
  const long long p0 = c64[0];
  const bool is64 = (p0 >= 0 && p0 < (1ll << 31));
  int c = 0;
  if (lane < 32) c = is64 ? (int)c64[lane] : counts[lane];
#pragma unroll
  for (int d = 1; d < 32; d <<= 1) {
    const int o = __shfl_up(c, d, 64);
    if (lane >= d) c += o;
  }
  const int cum = (lane < 32) ? c : 0x7fffffff;
  auto cumAt = [&](int i) { return __shfl(cum, i, 64); };

  auto POLL = [&](int g, int s) {
    while (vf[s] < g + 1) __builtin_amdgcn_s_sleep(1);
    asm volatile("" ::: "memory");
    __builtin_amdgcn_sched_barrier(0);
  };
  auto DONE = [&](int s) {
    asm volatile("" ::: "memory");
    if (lane == 0) atomicAdd(&sSync[4 + s], 1);
  };
  auto CVMW8 = [&]() { if (WSBF) { VMW("8"); } else { VMW("0"); } };

  int e = __popcll(__ballot(cum <= blk0));
  const u16*   wEL = wpk + ((size_t)e << 16) + (lane << 3);
  const float* wF  = w32 + ((size_t)e << 16);
  BF8 bA[2][4], bB[2][4];
  loadBstep<WSBF>(wEL, wF, wv, l15, lg, 0, bA);

  unsigned redo = 0;
  for (int t = 0; t < TPB; ++t) {
    const int t0 = blk0 + (t << 6);
    const int re = min(t0 + 64, cumAt(e));     // first run's end in this tile
    if (re < t0 + 64) redo |= (1u << t);

    f32x4 acc[4][4];
    const f32x4 zero = {0.f, 0.f, 0.f, 0.f};
#pragma unroll
    for (int m = 0; m < 4; ++m)
#pragma unroll
      for (int n = 0; n < 4; ++n) acc[m][n] = zero;

    // s=0
    loadBstep<WSBF>(wEL, wF, wv, l15, lg, 1, bB);
    POLL(4 * t + 0, 0); CVMW8();
    computeStep(sAc, 0, l15, lg, bA, acc);
    DONE(0);
    // s=1
    loadBstep<WSBF>(wEL, wF, wv, l15, lg, 2, bA);
    POLL(4 * t + 1, 1); CVMW8();
    computeStep(sAc, 1, l15, lg, bB, acc);
    DONE(1);
    // s=2
    loadBstep<WSBF>(wEL, wF, wv, l15, lg, 3, bB);
    POLL(4 * t + 2, 2); CVMW8();
    computeStep(sAc, 2, l15, lg, bA, acc);
    DONE(2);
    // s=3 (+ next-tile B0 prefetch)
    int eN = e;
    if (t < TPB - 1) {
      eN = __popcll(__ballot(cum <= t0 + 64));
      const u16*   wELn = wpk + ((size_t)eN << 16) + (lane << 3);
      const float* wFn  = w32 + ((size_t)eN << 16);
      loadBstep<WSBF>(wELn, wFn, wv, l15, lg, 0, bA);
      POLL(4 * t + 3, 3); CVMW8();
      computeStep(sAc, 3, l15, lg, bB, acc);
    } else {
      POLL(4 * t + 3, 3); VMW("0");
      computeStep(sAc, 3, l15, lg, bB, acc);
    }
    DONE(3);

    // ---- store (C/D map: col=l15, row=lg*4+j) ----
    if (re == t0 + 64) {
#pragma unroll
      for (int m = 0; m < 4; ++m) {
        const int rbase = t0 + (m << 4) + (lg << 2);
#pragma unroll
        for (int n = 0; n < 4; ++n) {
          float* op = out + (size_t)rbase * NOUT + (wv << 6) + (n << 4) + l15;
#pragma unroll
          for (int j = 0; j < 4; ++j) op[(size_t)j * NOUT] = acc[m][n][j];
        }
      }
    } else {
#pragma unroll
      for (int m = 0; m < 4; ++m) {
        const int rbase = t0 + (m << 4) + (lg << 2);
#pragma unroll
        for (int n = 0; n < 4; ++n) {
          float* op = out + (size_t)rbase * NOUT + (wv << 6) + (n << 4) + l15;
#pragma unroll
          for (int j = 0; j < 4; ++j)
            if (rbase + j < re) op[(size_t)j * NOUT] = acc[m][n][j];
        }
      }
    }
    e = eN;
    wEL = wpk + ((size_t)e << 16) + (lane << 3);
    wF  = w32 + ((size_t)e << 16);
  }

  // ---- boundary-tile remainder runs (rare; global-gather path) ----
  while (redo) {
    const int t = __builtin_ctz(redo); redo &= redo - 1;
    const int t0 = blk0 + (t << 6), t1 = t0 + 64;
    int ee = __popcll(__ballot(cum <= t0));
    int rbX = min(t1, cumAt(ee));
    while (rbX < t1) {
      ++ee;
      const int reX = min(t1, cumAt(ee));
      if (reX > rbX)
        redoRun2<WSBF>(inp, wpk, w32, t0, rbX, reX, ee, out, wv, l15, lg, lane);
      rbX = reX > rbX ? reX : rbX;
    }
  }
}

extern "C" void kernel_launch(void* const* d_in, const int* in_sizes, int n_in,
                              void* d_out, int out_size, void* d_ws, size_t ws_size,
                              hipStream_t stream) {
  const float* inp    = (const float*)d_in[0];
  const float* w      = (const float*)d_in[1];
  const int*   counts = (const int*)d_in[2];
  float*       out    = (float*)d_out;

  const size_t wbytes = (size_t)NEXPERT * NOUT * KIN * 2;  // 4 MB packed bf16 W
  const bool usews = (ws_size >= wbytes);
  const int grid = NTOK / (64 * TPB);   // 1024

  if (usews) {
    u16* wpk = (u16*)d_ws;
    pack_w_kernel<<<1024, 256, 0, stream>>>(w, wpk);
    moe_gemm_kernel<true><<<grid, 320, 0, stream>>>(inp, w, wpk, counts, out);
  } else {
    moe_gemm_kernel<false><<<grid, 320, 0, stream>>>(inp, w, nullptr, counts, out);
  }
}